// Round 5
// baseline (2532.937 us; speedup 1.0000x reference)
//
#include <hip/hip_runtime.h>

// LSS voxel pooling: scatter-add 996864 points x 64ch into [B=4, C=64, X=150, Y=200] fp32.
// Binning hypothesis (round 5): gold canonicalizes divide-by-constant to
// MULTIPLY-BY-RECIPROCAL in f32:  q = RN32((g - off) * RN32(1/d)); trunc.
// (All correctly-rounded-division variants f32/f64 gave bit-identical absmax
//  3.363281 -> gold sits at a systematic negative quotient shift ~ recip error.)

#define NPRIME 996864
#define NCH 64
#define NX0 150
#define NX1 200
#define CELLS_PER_B (NX0 * NX1)        // 30000
#define BATCH_STRIDE (NPRIME / 4)      // 249216 points per batch

// f32 reciprocal constants, folded at compile time with IEEE RN:
// 1.0f/0.6f  = 1.66666662693023681640625  (rel err -2.4e-8)
// 1.0f/0.15f = 6.66666650772094726562500  (rel err -2.4e-8)
// 1.0f/20.0f = 0.05f (exact)
__device__ __forceinline__ int bin_recip(float v, float off, float rcp) {
    float num = v - off;       // f32 RN subtract (matches numpy f32 / XLA)
    float q   = num * rcp;     // f32 RN multiply by reciprocal constant
    return (int)q;             // trunc toward zero == astype(int32)
}

__global__ __launch_bounds__(256) void lss_bin(
    const float* __restrict__ geom,    // [NPRIME, 3]
    int* __restrict__ cell)            // [NPRIME] packed b*30000 + x*200 + y, or -1
{
    int p = blockIdx.x * 256 + threadIdx.x;
    if (p >= NPRIME) return;
    float gx = geom[3 * p + 0];
    float gy = geom[3 * p + 1];
    float gz = geom[3 * p + 2];

    int i0 = bin_recip(gx,   0.0f, 1.0f / 0.6f);
    int i1 = bin_recip(gy, -15.0f, 1.0f / 0.15f);   // offy folds to -15.0f exactly
    int i2 = bin_recip(gz, -10.0f, 1.0f / 20.0f);

    bool kept = (i0 >= 0) & (i0 < NX0) & (i1 >= 0) & (i1 < NX1) & (i2 >= 0) & (i2 < 1);
    int b = p / BATCH_STRIDE;
    cell[p] = kept ? (b * CELLS_PER_B + i0 * NX1 + i1) : -1;
}

__global__ __launch_bounds__(256) void lss_scatter(
    const float* __restrict__ x,       // [NPRIME, 64]
    const int* __restrict__ cell,      // [NPRIME]
    float* __restrict__ out)           // [4, 64, 150, 200]
{
    int t = blockIdx.x * 256 + threadIdx.x;
    int p = t >> 4;                    // 16 threads per point
    if (p >= NPRIME) return;
    int c = cell[p];                   // broadcast across the 16 lanes via cache
    if (c < 0) return;
    int c4 = (t & 15) << 2;

    const float4 xv = *reinterpret_cast<const float4*>(x + (size_t)p * NCH + c4);

    int b  = c / CELLS_PER_B;
    int xy = c - b * CELLS_PER_B;
    float* o = out + ((size_t)(b * NCH + c4)) * CELLS_PER_B + xy;
    atomicAdd(o,                    xv.x);
    atomicAdd(o +     CELLS_PER_B,  xv.y);
    atomicAdd(o + 2 * CELLS_PER_B,  xv.z);
    atomicAdd(o + 3 * CELLS_PER_B,  xv.w);
}

// Fallback (ws too small): fused kernel, 16 threads/point each redo the binning.
__global__ __launch_bounds__(256) void lss_fused(
    const float* __restrict__ geom, const float* __restrict__ x,
    float* __restrict__ out)
{
    int t = blockIdx.x * 256 + threadIdx.x;
    int p = t >> 4;
    if (p >= NPRIME) return;
    float gx = geom[3 * p + 0];
    float gy = geom[3 * p + 1];
    float gz = geom[3 * p + 2];
    int i0 = bin_recip(gx,   0.0f, 1.0f / 0.6f);
    int i1 = bin_recip(gy, -15.0f, 1.0f / 0.15f);
    int i2 = bin_recip(gz, -10.0f, 1.0f / 20.0f);
    if (!((i0 >= 0) & (i0 < NX0) & (i1 >= 0) & (i1 < NX1) & (i2 >= 0) & (i2 < 1))) return;
    int b = p / BATCH_STRIDE;
    int c4 = (t & 15) << 2;
    const float4 xv = *reinterpret_cast<const float4*>(x + (size_t)p * NCH + c4);
    float* o = out + ((size_t)(b * NCH + c4)) * CELLS_PER_B + (i0 * NX1 + i1);
    atomicAdd(o,                    xv.x);
    atomicAdd(o +     CELLS_PER_B,  xv.y);
    atomicAdd(o + 2 * CELLS_PER_B,  xv.z);
    atomicAdd(o + 3 * CELLS_PER_B,  xv.w);
}

extern "C" void kernel_launch(void* const* d_in, const int* in_sizes, int n_in,
                              void* d_out, int out_size, void* d_ws, size_t ws_size,
                              hipStream_t stream) {
    const float* geom = (const float*)d_in[0];
    const float* x    = (const float*)d_in[1];
    float* out = (float*)d_out;

    hipMemsetAsync(d_out, 0, (size_t)out_size * sizeof(float), stream);

    if (ws_size >= (size_t)NPRIME * sizeof(int)) {
        int* cell = (int*)d_ws;
        lss_bin<<<(NPRIME + 255) / 256, 256, 0, stream>>>(geom, cell);
        const int threads2 = NPRIME * 16;
        lss_scatter<<<(threads2 + 255) / 256, 256, 0, stream>>>(x, cell, out);
    } else {
        const int threads = NPRIME * 16;
        lss_fused<<<(threads + 255) / 256, 256, 0, stream>>>(geom, x, out);
    }
}

// Round 6
// 737.013 us; speedup vs baseline: 3.4368x; 3.4368x over previous
//
#include <hip/hip_runtime.h>

// LSS voxel pooling: 996864 points x 64ch -> [B=4, C=64, X=150, Y=200] fp32.
// v6: channel-contiguous accumulator acc[B][XY][64] in ws (atomics hit 4 full
// 64B lines per point instead of 64 scattered 32B sectors), then LDS-tiled
// transpose to out[B][C][XY]. Binning = f32 multiply-by-reciprocal (validated r5).

#define NPRIME 996864
#define NCH 64
#define NX0 150
#define NX1 200
#define CELLS_PER_B (NX0 * NX1)          // 30000
#define NCELLS (4 * CELLS_PER_B)         // 120000
#define BATCH_STRIDE (NPRIME / 4)        // 249216
#define ACC_BYTES ((size_t)NCELLS * NCH * 4)   // 30,720,000
#define CELL_BYTES ((size_t)NPRIME * 4)        // 3,987,456

__device__ __forceinline__ int bin_recip(float v, float off, float rcp) {
    float num = v - off;       // f32 RN subtract
    float q   = num * rcp;     // f32 RN multiply by folded reciprocal
    return (int)q;             // trunc toward zero
}

__global__ __launch_bounds__(256) void lss_bin(
    const float* __restrict__ geom,      // [NPRIME, 3]
    int* __restrict__ cell)              // [NPRIME] packed b*30000 + x*200 + y, or -1
{
    int p = blockIdx.x * 256 + threadIdx.x;
    if (p >= NPRIME) return;
    float gx = geom[3 * p + 0];
    float gy = geom[3 * p + 1];
    float gz = geom[3 * p + 2];

    int i0 = bin_recip(gx,   0.0f, 1.0f / 0.6f);
    int i1 = bin_recip(gy, -15.0f, 1.0f / 0.15f);
    int i2 = bin_recip(gz, -10.0f, 1.0f / 20.0f);

    bool kept = (i0 >= 0) & (i0 < NX0) & (i1 >= 0) & (i1 < NX1) & (i2 >= 0) & (i2 < 1);
    int b = p / BATCH_STRIDE;
    cell[p] = kept ? (b * CELLS_PER_B + i0 * NX1 + i1) : -1;
}

// Scatter into acc[cell][c] (channel-contiguous): 16 threads/point, float4 each.
__global__ __launch_bounds__(256) void lss_scatter_acc(
    const float* __restrict__ x,         // [NPRIME, 64]
    const int* __restrict__ cell,        // [NPRIME]
    float* __restrict__ acc)             // [NCELLS, 64]
{
    int t = blockIdx.x * 256 + threadIdx.x;
    int p = t >> 4;
    if (p >= NPRIME) return;
    int c = cell[p];
    if (c < 0) return;
    int c4 = (t & 15) << 2;

    const float4 xv = *reinterpret_cast<const float4*>(x + (size_t)p * NCH + c4);
    float* a = acc + (size_t)c * NCH + c4;
    atomicAdd(a + 0, xv.x);
    atomicAdd(a + 1, xv.y);
    atomicAdd(a + 2, xv.z);
    atomicAdd(a + 3, xv.w);
}

// Transpose acc[b][xy][c] -> out[b][c][xy], 64x64 tiles via LDS.
__global__ __launch_bounds__(256) void lss_transpose(
    const float* __restrict__ acc,       // [4, 30000, 64]
    float* __restrict__ out)             // [4, 64, 30000]
{
    __shared__ float tile[64][65];
    int b   = blockIdx.y;
    int xy0 = blockIdx.x * 64;
    int t   = threadIdx.x;
    int lane16 = t & 15;
    int grp    = t >> 4;                 // 0..15

    #pragma unroll
    for (int pass = 0; pass < 4; ++pass) {
        int xyl = grp + 16 * pass;       // 0..63
        int xy  = xy0 + xyl;
        int c4  = lane16 * 4;
        if (xy < CELLS_PER_B) {
            float4 v = *reinterpret_cast<const float4*>(
                acc + ((size_t)b * CELLS_PER_B + xy) * NCH + c4);
            tile[xyl][c4 + 0] = v.x;
            tile[xyl][c4 + 1] = v.y;
            tile[xyl][c4 + 2] = v.z;
            tile[xyl][c4 + 3] = v.w;
        }
    }
    __syncthreads();
    #pragma unroll
    for (int pass = 0; pass < 4; ++pass) {
        int c   = grp + 16 * pass;       // 0..63
        int xyl = lane16 * 4;
        int xy  = xy0 + xyl;
        float4 w;
        w.x = tile[xyl + 0][c];
        w.y = tile[xyl + 1][c];
        w.z = tile[xyl + 2][c];
        w.w = tile[xyl + 3][c];
        float* op = out + ((size_t)(b * NCH + c)) * CELLS_PER_B + xy;
        if (xy + 3 < CELLS_PER_B) {
            *reinterpret_cast<float4*>(op) = w;
        } else {
            const float* wf = (const float*)&w;
            for (int k = 0; k < 4; ++k)
                if (xy + k < CELLS_PER_B) op[k] = wf[k];
        }
    }
}

// ---- fallbacks (small ws) ----
__global__ __launch_bounds__(256) void lss_scatter_direct(
    const float* __restrict__ x, const int* __restrict__ cell,
    float* __restrict__ out)
{
    int t = blockIdx.x * 256 + threadIdx.x;
    int p = t >> 4;
    if (p >= NPRIME) return;
    int c = cell[p];
    if (c < 0) return;
    int c4 = (t & 15) << 2;
    const float4 xv = *reinterpret_cast<const float4*>(x + (size_t)p * NCH + c4);
    int b  = c / CELLS_PER_B;
    int xy = c - b * CELLS_PER_B;
    float* o = out + ((size_t)(b * NCH + c4)) * CELLS_PER_B + xy;
    atomicAdd(o,                   xv.x);
    atomicAdd(o +     CELLS_PER_B, xv.y);
    atomicAdd(o + 2 * CELLS_PER_B, xv.z);
    atomicAdd(o + 3 * CELLS_PER_B, xv.w);
}

__global__ __launch_bounds__(256) void lss_fused(
    const float* __restrict__ geom, const float* __restrict__ x,
    float* __restrict__ out)
{
    int t = blockIdx.x * 256 + threadIdx.x;
    int p = t >> 4;
    if (p >= NPRIME) return;
    float gx = geom[3 * p + 0];
    float gy = geom[3 * p + 1];
    float gz = geom[3 * p + 2];
    int i0 = bin_recip(gx,   0.0f, 1.0f / 0.6f);
    int i1 = bin_recip(gy, -15.0f, 1.0f / 0.15f);
    int i2 = bin_recip(gz, -10.0f, 1.0f / 20.0f);
    if (!((i0 >= 0) & (i0 < NX0) & (i1 >= 0) & (i1 < NX1) & (i2 >= 0) & (i2 < 1))) return;
    int b = p / BATCH_STRIDE;
    int c4 = (t & 15) << 2;
    const float4 xv = *reinterpret_cast<const float4*>(x + (size_t)p * NCH + c4);
    float* o = out + ((size_t)(b * NCH + c4)) * CELLS_PER_B + (i0 * NX1 + i1);
    atomicAdd(o,                   xv.x);
    atomicAdd(o +     CELLS_PER_B, xv.y);
    atomicAdd(o + 2 * CELLS_PER_B, xv.z);
    atomicAdd(o + 3 * CELLS_PER_B, xv.w);
}

extern "C" void kernel_launch(void* const* d_in, const int* in_sizes, int n_in,
                              void* d_out, int out_size, void* d_ws, size_t ws_size,
                              hipStream_t stream) {
    const float* geom = (const float*)d_in[0];
    const float* x    = (const float*)d_in[1];
    float* out = (float*)d_out;

    const int bin_blocks  = (NPRIME + 255) / 256;
    const int scat_blocks = (NPRIME * 16 + 255) / 256;

    if (ws_size >= ACC_BYTES + CELL_BYTES) {
        float* acc = (float*)d_ws;
        int* cell  = (int*)((char*)d_ws + ACC_BYTES);
        hipMemsetAsync(acc, 0, ACC_BYTES, stream);
        lss_bin<<<bin_blocks, 256, 0, stream>>>(geom, cell);
        lss_scatter_acc<<<scat_blocks, 256, 0, stream>>>(x, cell, acc);
        dim3 tgrid((CELLS_PER_B + 63) / 64, 4);
        lss_transpose<<<tgrid, 256, 0, stream>>>(acc, out);
    } else if (ws_size >= CELL_BYTES) {
        int* cell = (int*)d_ws;
        hipMemsetAsync(d_out, 0, (size_t)out_size * sizeof(float), stream);
        lss_bin<<<bin_blocks, 256, 0, stream>>>(geom, cell);
        lss_scatter_direct<<<scat_blocks, 256, 0, stream>>>(x, cell, out);
    } else {
        hipMemsetAsync(d_out, 0, (size_t)out_size * sizeof(float), stream);
        lss_fused<<<scat_blocks, 256, 0, stream>>>(geom, x, out);
    }
}

// Round 7
// 230.834 us; speedup vs baseline: 10.9730x; 3.1928x over previous
//
#include <hip/hip_runtime.h>

// LSS voxel pooling: 996864 points x 64ch -> [B=4, C=64, X=150, Y=200] fp32.
// v7: scatter with 64 threads/point (1 float, 1 atomic each) -> one wave = one
// point, its atomic instruction covers a contiguous 256B span so each 32B
// sector is touched by exactly ONE instruction (v6's 16x4 layout touched each
// sector 4x -> 1KB/point). Then LDS-tiled transpose acc[b][xy][c]->out[b][c][xy].
// Binning = f32 multiply-by-reciprocal (validated round 5).

#define NPRIME 996864
#define NCH 64
#define NX0 150
#define NX1 200
#define CELLS_PER_B (NX0 * NX1)          // 30000
#define NCELLS (4 * CELLS_PER_B)         // 120000
#define BATCH_STRIDE (NPRIME / 4)        // 249216
#define ACC_BYTES ((size_t)NCELLS * NCH * 4)   // 30,720,000
#define CELL_BYTES ((size_t)NPRIME * 4)        // 3,987,456

__device__ __forceinline__ int bin_recip(float v, float off, float rcp) {
    float num = v - off;       // f32 RN subtract
    float q   = num * rcp;     // f32 RN multiply by folded reciprocal
    return (int)q;             // trunc toward zero
}

__global__ __launch_bounds__(256) void lss_bin(
    const float* __restrict__ geom,      // [NPRIME, 3]
    int* __restrict__ cell)              // [NPRIME] packed b*30000 + x*200 + y, or -1
{
    int p = blockIdx.x * 256 + threadIdx.x;
    if (p >= NPRIME) return;
    float gx = geom[3 * p + 0];
    float gy = geom[3 * p + 1];
    float gz = geom[3 * p + 2];

    int i0 = bin_recip(gx,   0.0f, 1.0f / 0.6f);
    int i1 = bin_recip(gy, -15.0f, 1.0f / 0.15f);
    int i2 = bin_recip(gz, -10.0f, 1.0f / 20.0f);

    bool kept = (i0 >= 0) & (i0 < NX0) & (i1 >= 0) & (i1 < NX1) & (i2 >= 0) & (i2 < 1);
    int b = p / BATCH_STRIDE;
    cell[p] = kept ? (b * CELLS_PER_B + i0 * NX1 + i1) : -1;
}

// Scatter into acc[cell][c]: 64 threads/point, one 4B atomic each.
// A wave's 64 lanes cover one point's full 256B contiguous channel block.
__global__ __launch_bounds__(256) void lss_scatter_acc(
    const float* __restrict__ x,         // [NPRIME, 64]
    const int* __restrict__ cell,        // [NPRIME]
    float* __restrict__ acc)             // [NCELLS, 64]
{
    long long t = (long long)blockIdx.x * 256 + threadIdx.x;
    int p = (int)(t >> 6);
    if (p >= NPRIME) return;
    int c = cell[p];                     // wave-uniform (one point per wave)
    if (c < 0) return;
    int ch = (int)(t & 63);

    float v = x[(size_t)p * NCH + ch];   // coalesced: 256B per wave
    atomicAdd(acc + (size_t)c * NCH + ch, v);
}

// Transpose acc[b][xy][c] -> out[b][c][xy], 64x64 tiles via LDS.
__global__ __launch_bounds__(256) void lss_transpose(
    const float* __restrict__ acc,       // [4, 30000, 64]
    float* __restrict__ out)             // [4, 64, 30000]
{
    __shared__ float tile[64][65];
    int b   = blockIdx.y;
    int xy0 = blockIdx.x * 64;
    int t   = threadIdx.x;
    int lane16 = t & 15;
    int grp    = t >> 4;                 // 0..15

    #pragma unroll
    for (int pass = 0; pass < 4; ++pass) {
        int xyl = grp + 16 * pass;       // 0..63
        int xy  = xy0 + xyl;
        int c4  = lane16 * 4;
        if (xy < CELLS_PER_B) {
            float4 v = *reinterpret_cast<const float4*>(
                acc + ((size_t)b * CELLS_PER_B + xy) * NCH + c4);
            tile[xyl][c4 + 0] = v.x;
            tile[xyl][c4 + 1] = v.y;
            tile[xyl][c4 + 2] = v.z;
            tile[xyl][c4 + 3] = v.w;
        }
    }
    __syncthreads();
    #pragma unroll
    for (int pass = 0; pass < 4; ++pass) {
        int c   = grp + 16 * pass;       // 0..63
        int xyl = lane16 * 4;
        int xy  = xy0 + xyl;
        float4 w;
        w.x = tile[xyl + 0][c];
        w.y = tile[xyl + 1][c];
        w.z = tile[xyl + 2][c];
        w.w = tile[xyl + 3][c];
        float* op = out + ((size_t)(b * NCH + c)) * CELLS_PER_B + xy;
        if (xy + 3 < CELLS_PER_B) {
            *reinterpret_cast<float4*>(op) = w;
        } else {
            const float* wf = (const float*)&w;
            for (int k = 0; k < 4; ++k)
                if (xy + k < CELLS_PER_B) op[k] = wf[k];
        }
    }
}

// ---- fallbacks (small ws) ----
__global__ __launch_bounds__(256) void lss_scatter_direct(
    const float* __restrict__ x, const int* __restrict__ cell,
    float* __restrict__ out)
{
    int t = blockIdx.x * 256 + threadIdx.x;
    int p = t >> 4;
    if (p >= NPRIME) return;
    int c = cell[p];
    if (c < 0) return;
    int c4 = (t & 15) << 2;
    const float4 xv = *reinterpret_cast<const float4*>(x + (size_t)p * NCH + c4);
    int b  = c / CELLS_PER_B;
    int xy = c - b * CELLS_PER_B;
    float* o = out + ((size_t)(b * NCH + c4)) * CELLS_PER_B + xy;
    atomicAdd(o,                   xv.x);
    atomicAdd(o +     CELLS_PER_B, xv.y);
    atomicAdd(o + 2 * CELLS_PER_B, xv.z);
    atomicAdd(o + 3 * CELLS_PER_B, xv.w);
}

__global__ __launch_bounds__(256) void lss_fused(
    const float* __restrict__ geom, const float* __restrict__ x,
    float* __restrict__ out)
{
    int t = blockIdx.x * 256 + threadIdx.x;
    int p = t >> 4;
    if (p >= NPRIME) return;
    float gx = geom[3 * p + 0];
    float gy = geom[3 * p + 1];
    float gz = geom[3 * p + 2];
    int i0 = bin_recip(gx,   0.0f, 1.0f / 0.6f);
    int i1 = bin_recip(gy, -15.0f, 1.0f / 0.15f);
    int i2 = bin_recip(gz, -10.0f, 1.0f / 20.0f);
    if (!((i0 >= 0) & (i0 < NX0) & (i1 >= 0) & (i1 < NX1) & (i2 >= 0) & (i2 < 1))) return;
    int b = p / BATCH_STRIDE;
    int c4 = (t & 15) << 2;
    const float4 xv = *reinterpret_cast<const float4*>(x + (size_t)p * NCH + c4);
    float* o = out + ((size_t)(b * NCH + c4)) * CELLS_PER_B + (i0 * NX1 + i1);
    atomicAdd(o,                   xv.x);
    atomicAdd(o +     CELLS_PER_B, xv.y);
    atomicAdd(o + 2 * CELLS_PER_B, xv.z);
    atomicAdd(o + 3 * CELLS_PER_B, xv.w);
}

extern "C" void kernel_launch(void* const* d_in, const int* in_sizes, int n_in,
                              void* d_out, int out_size, void* d_ws, size_t ws_size,
                              hipStream_t stream) {
    const float* geom = (const float*)d_in[0];
    const float* x    = (const float*)d_in[1];
    float* out = (float*)d_out;

    const int bin_blocks = (NPRIME + 255) / 256;

    if (ws_size >= ACC_BYTES + CELL_BYTES) {
        float* acc = (float*)d_ws;
        int* cell  = (int*)((char*)d_ws + ACC_BYTES);
        hipMemsetAsync(acc, 0, ACC_BYTES, stream);
        lss_bin<<<bin_blocks, 256, 0, stream>>>(geom, cell);
        const long long threads2 = (long long)NPRIME * 64;
        const int blocks2 = (int)((threads2 + 255) / 256);   // 249216 blocks
        lss_scatter_acc<<<blocks2, 256, 0, stream>>>(x, cell, acc);
        dim3 tgrid((CELLS_PER_B + 63) / 64, 4);
        lss_transpose<<<tgrid, 256, 0, stream>>>(acc, out);
    } else if (ws_size >= CELL_BYTES) {
        int* cell = (int*)d_ws;
        hipMemsetAsync(d_out, 0, (size_t)out_size * sizeof(float), stream);
        lss_bin<<<bin_blocks, 256, 0, stream>>>(geom, cell);
        lss_scatter_direct<<<(NPRIME * 16 + 255) / 256, 256, 0, stream>>>(x, cell, out);
    } else {
        hipMemsetAsync(d_out, 0, (size_t)out_size * sizeof(float), stream);
        lss_fused<<<(NPRIME * 16 + 255) / 256, 256, 0, stream>>>(geom, x, out);
    }
}

// Round 8
// 145.849 us; speedup vs baseline: 17.3668x; 1.5827x over previous
//
#include <hip/hip_runtime.h>

// LSS voxel pooling: 996864 points x 64ch -> [B=4, C=64, X=150, Y=200] fp32.
// v8: bucket-then-reduce (kills the 52M-atomic fabric-RMW bottleneck).
//   k1: bin (f32 recip-mul, validated r5) + push point idx into per-cell slots
//       (816k u32 atomics instead of 52M f32 atomics).
//   k2: per-cell register reduction (lane=channel, coalesced 256B gathers),
//       fused transposed write out[b][c][xy] -- zero atomics, 30MB written.

#define NPRIME 996864
#define NCH 64
#define NX0 150
#define NX1 200
#define CELLS_PER_B (NX0 * NX1)          // 30000
#define NCELLS (4 * CELLS_PER_B)         // 120000
#define BATCH_STRIDE (NPRIME / 4)        // 249216
#define CAP 44                            // max pts/cell; Poisson(6.8): P(>=44)~1e-19
#define CNT_BYTES ((size_t)NCELLS * 4)               // 480,000
#define SLOT_BYTES ((size_t)NCELLS * CAP * 4)        // 21,120,000
#define ACC_BYTES ((size_t)NCELLS * NCH * 4)         // legacy fallback
#define CELL_BYTES ((size_t)NPRIME * 4)              // legacy fallback

__device__ __forceinline__ int bin_recip(float v, float off, float rcp) {
    float num = v - off;       // f32 RN subtract
    float q   = num * rcp;     // f32 RN multiply by folded reciprocal
    return (int)q;             // trunc toward zero
}

__device__ __forceinline__ int compute_cell(float gx, float gy, float gz, int p) {
    int i0 = bin_recip(gx,   0.0f, 1.0f / 0.6f);
    int i1 = bin_recip(gy, -15.0f, 1.0f / 0.15f);
    int i2 = bin_recip(gz, -10.0f, 1.0f / 20.0f);
    bool kept = (i0 >= 0) & (i0 < NX0) & (i1 >= 0) & (i1 < NX1) & (i2 >= 0) & (i2 < 1);
    int b = p / BATCH_STRIDE;
    return kept ? (b * CELLS_PER_B + i0 * NX1 + i1) : -1;
}

// k1: bin + push into per-cell slot lists.
__global__ __launch_bounds__(256) void lss_bin_push(
    const float* __restrict__ geom,      // [NPRIME, 3]
    unsigned* __restrict__ cnt,          // [NCELLS]
    int* __restrict__ slots)             // [NCELLS, CAP]
{
    int p = blockIdx.x * 256 + threadIdx.x;
    if (p >= NPRIME) return;
    float gx = geom[3 * p + 0];
    float gy = geom[3 * p + 1];
    float gz = geom[3 * p + 2];
    int c = compute_cell(gx, gy, gz, p);
    if (c < 0) return;
    unsigned pos = atomicAdd(&cnt[c], 1u);
    if (pos < CAP) slots[c * CAP + pos] = p;
}

// k2: reduce each cell's point list in registers; fused transposed write.
// Block = 1024 threads (16 waves) covers 64 consecutive xy cells of one batch.
__global__ __launch_bounds__(1024) void lss_accum(
    const float* __restrict__ x,         // [NPRIME, 64]
    const unsigned* __restrict__ cnt,    // [NCELLS]
    const int* __restrict__ slots,       // [NCELLS, CAP]
    float* __restrict__ out)             // [4, 64, 30000]
{
    __shared__ float tile[64][65];
    int b    = blockIdx.y;
    int xy0  = blockIdx.x * 64;
    int t    = threadIdx.x;
    int wave = t >> 6;                   // 0..15
    int lane = t & 63;                   // channel

    #pragma unroll
    for (int j = 0; j < 4; ++j) {
        int xyl = wave * 4 + j;
        int xy  = xy0 + xyl;
        float acc0 = 0.0f, acc1 = 0.0f;
        if (xy < CELLS_PER_B) {
            int cell = b * CELLS_PER_B + xy;
            int n = (int)cnt[cell];
            if (n > CAP) n = CAP;
            const int* sl = slots + (size_t)cell * CAP;
            int i = 0;
            for (; i + 1 < n; i += 2) {    // 2 loads in flight per wave
                int p0 = sl[i];
                int p1 = sl[i + 1];
                acc0 += x[(size_t)p0 * NCH + lane];
                acc1 += x[(size_t)p1 * NCH + lane];
            }
            if (i < n) acc0 += x[(size_t)sl[i] * NCH + lane];
        }
        tile[xyl][lane] = acc0 + acc1;
    }
    __syncthreads();

    // transposed write: thread t -> c = t>>4, xy_l = (t&15)*4 (float4)
    int c   = t >> 4;                    // 0..63
    int xyl = (t & 15) * 4;
    int xy  = xy0 + xyl;
    if (xy + 3 < CELLS_PER_B) {          // 30000 % 4 == 0 -> quads fully in/out
        float4 w;
        w.x = tile[xyl + 0][c];
        w.y = tile[xyl + 1][c];
        w.z = tile[xyl + 2][c];
        w.w = tile[xyl + 3][c];
        *reinterpret_cast<float4*>(out + ((size_t)(b * NCH + c)) * CELLS_PER_B + xy) = w;
    }
}

// ---- fallbacks (small ws), from validated v7 ----
__global__ __launch_bounds__(256) void lss_bin(
    const float* __restrict__ geom, int* __restrict__ cell)
{
    int p = blockIdx.x * 256 + threadIdx.x;
    if (p >= NPRIME) return;
    cell[p] = compute_cell(geom[3 * p], geom[3 * p + 1], geom[3 * p + 2], p);
}

__global__ __launch_bounds__(256) void lss_scatter_direct(
    const float* __restrict__ x, const int* __restrict__ cell,
    float* __restrict__ out)
{
    int t = blockIdx.x * 256 + threadIdx.x;
    int p = t >> 4;
    if (p >= NPRIME) return;
    int c = cell[p];
    if (c < 0) return;
    int c4 = (t & 15) << 2;
    const float4 xv = *reinterpret_cast<const float4*>(x + (size_t)p * NCH + c4);
    int b  = c / CELLS_PER_B;
    int xy = c - b * CELLS_PER_B;
    float* o = out + ((size_t)(b * NCH + c4)) * CELLS_PER_B + xy;
    atomicAdd(o,                   xv.x);
    atomicAdd(o +     CELLS_PER_B, xv.y);
    atomicAdd(o + 2 * CELLS_PER_B, xv.z);
    atomicAdd(o + 3 * CELLS_PER_B, xv.w);
}

__global__ __launch_bounds__(256) void lss_fused(
    const float* __restrict__ geom, const float* __restrict__ x,
    float* __restrict__ out)
{
    int t = blockIdx.x * 256 + threadIdx.x;
    int p = t >> 4;
    if (p >= NPRIME) return;
    int c = compute_cell(geom[3 * p], geom[3 * p + 1], geom[3 * p + 2], p);
    if (c < 0) return;
    int b  = c / CELLS_PER_B;
    int xy = c - b * CELLS_PER_B;
    int c4 = (t & 15) << 2;
    const float4 xv = *reinterpret_cast<const float4*>(x + (size_t)p * NCH + c4);
    float* o = out + ((size_t)(b * NCH + c4)) * CELLS_PER_B + xy;
    atomicAdd(o,                   xv.x);
    atomicAdd(o +     CELLS_PER_B, xv.y);
    atomicAdd(o + 2 * CELLS_PER_B, xv.z);
    atomicAdd(o + 3 * CELLS_PER_B, xv.w);
}

extern "C" void kernel_launch(void* const* d_in, const int* in_sizes, int n_in,
                              void* d_out, int out_size, void* d_ws, size_t ws_size,
                              hipStream_t stream) {
    const float* geom = (const float*)d_in[0];
    const float* x    = (const float*)d_in[1];
    float* out = (float*)d_out;

    const int bin_blocks = (NPRIME + 255) / 256;

    if (ws_size >= CNT_BYTES + SLOT_BYTES) {
        unsigned* cnt = (unsigned*)d_ws;
        int* slots    = (int*)((char*)d_ws + CNT_BYTES);
        hipMemsetAsync(cnt, 0, CNT_BYTES, stream);
        lss_bin_push<<<bin_blocks, 256, 0, stream>>>(geom, cnt, slots);
        dim3 agrid((CELLS_PER_B + 63) / 64, 4);      // 469 x 4
        lss_accum<<<agrid, 1024, 0, stream>>>(x, cnt, slots, out);
    } else if (ws_size >= CELL_BYTES) {
        int* cell = (int*)d_ws;
        hipMemsetAsync(d_out, 0, (size_t)out_size * sizeof(float), stream);
        lss_bin<<<bin_blocks, 256, 0, stream>>>(geom, cell);
        lss_scatter_direct<<<(NPRIME * 16 + 255) / 256, 256, 0, stream>>>(x, cell, out);
    } else {
        hipMemsetAsync(d_out, 0, (size_t)out_size * sizeof(float), stream);
        lss_fused<<<(NPRIME * 16 + 255) / 256, 256, 0, stream>>>(geom, x, out);
    }
}

// Round 9
// 125.929 us; speedup vs baseline: 20.1140x; 1.1582x over previous
//
#include <hip/hip_runtime.h>

// LSS voxel pooling: 996864 points x 64ch -> [B=4, C=64, X=150, Y=200] fp32.
// v9: v8 bucket-then-reduce, minus the hipMemsetAsync small-fill pathology
// (custom lss_zero kernel), plus masked unroll-4 gather pipeline in accum.
//   k0: zero cnt (120k u32) -- ~2us, replaces the 148us slow fill node.
//   k1: bin (f32 recip-mul, validated r5) + push point idx into per-cell slots.
//   k2: per-cell register reduction (lane=channel, coalesced 256B gathers),
//       fused transposed write out[b][c][xy] -- zero atomics.

#define NPRIME 996864
#define NCH 64
#define NX0 150
#define NX1 200
#define CELLS_PER_B (NX0 * NX1)          // 30000
#define NCELLS (4 * CELLS_PER_B)         // 120000
#define BATCH_STRIDE (NPRIME / 4)        // 249216
#define CAP 44                            // max pts/cell; Poisson(6.8): P(>=44)~1e-19
#define CNT_BYTES ((size_t)NCELLS * 4)               // 480,000
#define SLOT_BYTES ((size_t)NCELLS * CAP * 4)        // 21,120,000
#define CELL_BYTES ((size_t)NPRIME * 4)              // fallback

__device__ __forceinline__ int bin_recip(float v, float off, float rcp) {
    float num = v - off;       // f32 RN subtract
    float q   = num * rcp;     // f32 RN multiply by folded reciprocal
    return (int)q;             // trunc toward zero
}

__device__ __forceinline__ int compute_cell(float gx, float gy, float gz, int p) {
    int i0 = bin_recip(gx,   0.0f, 1.0f / 0.6f);
    int i1 = bin_recip(gy, -15.0f, 1.0f / 0.15f);
    int i2 = bin_recip(gz, -10.0f, 1.0f / 20.0f);
    bool kept = (i0 >= 0) & (i0 < NX0) & (i1 >= 0) & (i1 < NX1) & (i2 >= 0) & (i2 < 1);
    int b = p / BATCH_STRIDE;
    return kept ? (b * CELLS_PER_B + i0 * NX1 + i1) : -1;
}

// k0: zero the counters (replaces hipMemsetAsync -- small-size fill was ~148us).
__global__ __launch_bounds__(256) void lss_zero(unsigned* __restrict__ cnt) {
    int i = blockIdx.x * 256 + threadIdx.x;
    if (i < NCELLS) cnt[i] = 0u;
}

// k1: bin + push into per-cell slot lists.
__global__ __launch_bounds__(256) void lss_bin_push(
    const float* __restrict__ geom,      // [NPRIME, 3]
    unsigned* __restrict__ cnt,          // [NCELLS]
    int* __restrict__ slots)             // [NCELLS, CAP]
{
    int p = blockIdx.x * 256 + threadIdx.x;
    if (p >= NPRIME) return;
    float gx = geom[3 * p + 0];
    float gy = geom[3 * p + 1];
    float gz = geom[3 * p + 2];
    int c = compute_cell(gx, gy, gz, p);
    if (c < 0) return;
    unsigned pos = atomicAdd(&cnt[c], 1u);
    if (pos < CAP) slots[c * CAP + pos] = p;
}

// k2: reduce each cell's point list in registers; fused transposed write.
// Block = 1024 threads (16 waves) covers 64 consecutive xy cells of one batch.
// Masked unroll-4: 4 gathers in flight even through the tail.
__global__ __launch_bounds__(1024) void lss_accum(
    const float* __restrict__ x,         // [NPRIME, 64]
    const unsigned* __restrict__ cnt,    // [NCELLS]
    const int* __restrict__ slots,       // [NCELLS, CAP]
    float* __restrict__ out)             // [4, 64, 30000]
{
    __shared__ float tile[64][65];
    int b    = blockIdx.y;
    int xy0  = blockIdx.x * 64;
    int t    = threadIdx.x;
    int wave = t >> 6;                   // 0..15
    int lane = t & 63;                   // channel

    #pragma unroll
    for (int j = 0; j < 4; ++j) {
        int xyl = wave * 4 + j;
        int xy  = xy0 + xyl;
        float a0 = 0.0f, a1 = 0.0f, a2 = 0.0f, a3 = 0.0f;
        if (xy < CELLS_PER_B) {
            int cell = b * CELLS_PER_B + xy;
            int n = (int)cnt[cell];
            if (n > CAP) n = CAP;
            const int* sl = slots + (size_t)cell * CAP;
            for (int i = 0; i < n; i += 4) {
                // clamped indices keep 4 loads in flight; adds are predicated
                int i1 = i + 1 < n ? i + 1 : i;
                int i2 = i + 2 < n ? i + 2 : i;
                int i3 = i + 3 < n ? i + 3 : i;
                int p0 = sl[i],  p1 = sl[i1], p2 = sl[i2], p3 = sl[i3];
                float v0 = x[(size_t)p0 * NCH + lane];
                float v1 = x[(size_t)p1 * NCH + lane];
                float v2 = x[(size_t)p2 * NCH + lane];
                float v3 = x[(size_t)p3 * NCH + lane];
                a0 += v0;
                a1 += (i + 1 < n) ? v1 : 0.0f;
                a2 += (i + 2 < n) ? v2 : 0.0f;
                a3 += (i + 3 < n) ? v3 : 0.0f;
            }
        }
        tile[xyl][lane] = (a0 + a1) + (a2 + a3);
    }
    __syncthreads();

    // transposed write: thread t -> c = t>>4, xy_l = (t&15)*4 (float4)
    int c   = t >> 4;                    // 0..63
    int xyl = (t & 15) * 4;
    int xy  = xy0 + xyl;
    if (xy + 3 < CELLS_PER_B) {          // 30000 % 4 == 0
        float4 w;
        w.x = tile[xyl + 0][c];
        w.y = tile[xyl + 1][c];
        w.z = tile[xyl + 2][c];
        w.w = tile[xyl + 3][c];
        *reinterpret_cast<float4*>(out + ((size_t)(b * NCH + c)) * CELLS_PER_B + xy) = w;
    }
}

// ---- fallback (small ws), validated v7 path ----
__global__ __launch_bounds__(256) void lss_bin(
    const float* __restrict__ geom, int* __restrict__ cell)
{
    int p = blockIdx.x * 256 + threadIdx.x;
    if (p >= NPRIME) return;
    cell[p] = compute_cell(geom[3 * p], geom[3 * p + 1], geom[3 * p + 2], p);
}

__global__ __launch_bounds__(256) void lss_scatter_direct(
    const float* __restrict__ x, const int* __restrict__ cell,
    float* __restrict__ out)
{
    int t = blockIdx.x * 256 + threadIdx.x;
    int p = t >> 4;
    if (p >= NPRIME) return;
    int c = cell[p];
    if (c < 0) return;
    int c4 = (t & 15) << 2;
    const float4 xv = *reinterpret_cast<const float4*>(x + (size_t)p * NCH + c4);
    int b  = c / CELLS_PER_B;
    int xy = c - b * CELLS_PER_B;
    float* o = out + ((size_t)(b * NCH + c4)) * CELLS_PER_B + xy;
    atomicAdd(o,                   xv.x);
    atomicAdd(o +     CELLS_PER_B, xv.y);
    atomicAdd(o + 2 * CELLS_PER_B, xv.z);
    atomicAdd(o + 3 * CELLS_PER_B, xv.w);
}

__global__ __launch_bounds__(256) void lss_fused(
    const float* __restrict__ geom, const float* __restrict__ x,
    float* __restrict__ out)
{
    int t = blockIdx.x * 256 + threadIdx.x;
    int p = t >> 4;
    if (p >= NPRIME) return;
    int c = compute_cell(geom[3 * p], geom[3 * p + 1], geom[3 * p + 2], p);
    if (c < 0) return;
    int b  = c / CELLS_PER_B;
    int xy = c - b * CELLS_PER_B;
    int c4 = (t & 15) << 2;
    const float4 xv = *reinterpret_cast<const float4*>(x + (size_t)p * NCH + c4);
    float* o = out + ((size_t)(b * NCH + c4)) * CELLS_PER_B + xy;
    atomicAdd(o,                   xv.x);
    atomicAdd(o +     CELLS_PER_B, xv.y);
    atomicAdd(o + 2 * CELLS_PER_B, xv.z);
    atomicAdd(o + 3 * CELLS_PER_B, xv.w);
}

extern "C" void kernel_launch(void* const* d_in, const int* in_sizes, int n_in,
                              void* d_out, int out_size, void* d_ws, size_t ws_size,
                              hipStream_t stream) {
    const float* geom = (const float*)d_in[0];
    const float* x    = (const float*)d_in[1];
    float* out = (float*)d_out;

    const int bin_blocks = (NPRIME + 255) / 256;

    if (ws_size >= CNT_BYTES + SLOT_BYTES) {
        unsigned* cnt = (unsigned*)d_ws;
        int* slots    = (int*)((char*)d_ws + CNT_BYTES);
        lss_zero<<<(NCELLS + 255) / 256, 256, 0, stream>>>(cnt);
        lss_bin_push<<<bin_blocks, 256, 0, stream>>>(geom, cnt, slots);
        dim3 agrid((CELLS_PER_B + 63) / 64, 4);      // 469 x 4
        lss_accum<<<agrid, 1024, 0, stream>>>(x, cnt, slots, out);
    } else if (ws_size >= CELL_BYTES) {
        int* cell = (int*)d_ws;
        hipMemsetAsync(d_out, 0, (size_t)out_size * sizeof(float), stream);
        lss_bin<<<bin_blocks, 256, 0, stream>>>(geom, cell);
        lss_scatter_direct<<<(NPRIME * 16 + 255) / 256, 256, 0, stream>>>(x, cell, out);
    } else {
        hipMemsetAsync(d_out, 0, (size_t)out_size * sizeof(float), stream);
        lss_fused<<<(NPRIME * 16 + 255) / 256, 256, 0, stream>>>(geom, x, out);
    }
}

// Round 10
// 117.282 us; speedup vs baseline: 21.5969x; 1.0737x over previous
//
#include <hip/hip_runtime.h>

// LSS voxel pooling: 996864 points x 64ch -> [B=4, C=64, X=150, Y=200] fp32.
// v10: accum restructured breadth-first -- each wave reduces TWO cells with
// interleaved independent load chains (8 gathers in flight), clamped-index
// tails (L2-hot re-reads). Kills the serialized per-cell dependence chains of
// v9's unrolled j-loop. bin_push / zero / binning math (r5-validated) unchanged.

#define NPRIME 996864
#define NCH 64
#define NX0 150
#define NX1 200
#define CELLS_PER_B (NX0 * NX1)          // 30000
#define NCELLS (4 * CELLS_PER_B)         // 120000
#define BATCH_STRIDE (NPRIME / 4)        // 249216
#define CAP 44                            // max pts/cell; Poisson(6.8): P(>=44)~1e-19
#define CNT_BYTES ((size_t)NCELLS * 4)               // 480,000
#define SLOT_BYTES ((size_t)NCELLS * CAP * 4)        // 21,120,000
#define CELL_BYTES ((size_t)NPRIME * 4)              // fallback

__device__ __forceinline__ int bin_recip(float v, float off, float rcp) {
    float num = v - off;       // f32 RN subtract
    float q   = num * rcp;     // f32 RN multiply by folded reciprocal
    return (int)q;             // trunc toward zero
}

__device__ __forceinline__ int compute_cell(float gx, float gy, float gz, int p) {
    int i0 = bin_recip(gx,   0.0f, 1.0f / 0.6f);
    int i1 = bin_recip(gy, -15.0f, 1.0f / 0.15f);
    int i2 = bin_recip(gz, -10.0f, 1.0f / 20.0f);
    bool kept = (i0 >= 0) & (i0 < NX0) & (i1 >= 0) & (i1 < NX1) & (i2 >= 0) & (i2 < 1);
    int b = p / BATCH_STRIDE;
    return kept ? (b * CELLS_PER_B + i0 * NX1 + i1) : -1;
}

// k0: zero the counters.
__global__ __launch_bounds__(256) void lss_zero(unsigned* __restrict__ cnt) {
    int i = blockIdx.x * 256 + threadIdx.x;
    if (i < NCELLS) cnt[i] = 0u;
}

// k1: bin + push into per-cell slot lists.
__global__ __launch_bounds__(256) void lss_bin_push(
    const float* __restrict__ geom,      // [NPRIME, 3]
    unsigned* __restrict__ cnt,          // [NCELLS]
    int* __restrict__ slots)             // [NCELLS, CAP]
{
    int p = blockIdx.x * 256 + threadIdx.x;
    if (p >= NPRIME) return;
    float gx = geom[3 * p + 0];
    float gy = geom[3 * p + 1];
    float gz = geom[3 * p + 2];
    int c = compute_cell(gx, gy, gz, p);
    if (c < 0) return;
    unsigned pos = atomicAdd(&cnt[c], 1u);
    if (pos < CAP) slots[c * CAP + pos] = p;
}

// k2: breadth-first reduction. Block = 1024 thr (16 waves) covers 32 cells;
// each wave owns 2 cells and keeps 8 gathers in flight across both.
__global__ __launch_bounds__(1024) void lss_accum(
    const float* __restrict__ x,         // [NPRIME, 64]
    const unsigned* __restrict__ cnt,    // [NCELLS]
    const int* __restrict__ slots,       // [NCELLS, CAP]
    float* __restrict__ out)             // [4, 64, 30000]
{
    __shared__ float tile[32][65];
    int b    = blockIdx.y;
    int xy0  = blockIdx.x * 32;
    int t    = threadIdx.x;
    int wave = t >> 6;                   // 0..15
    int lane = t & 63;                   // channel

    int xyA = xy0 + wave * 2;
    int xyB = xyA + 1;
    int cellA = b * CELLS_PER_B + xyA;
    int cellB = b * CELLS_PER_B + xyB;
    int nA = (xyA < CELLS_PER_B) ? (int)cnt[cellA] : 0;
    int nB = (xyB < CELLS_PER_B) ? (int)cnt[cellB] : 0;
    nA = nA > CAP ? CAP : nA;
    nB = nB > CAP ? CAP : nB;
    const int* slA = slots + (size_t)cellA * CAP;
    const int* slB = slots + (size_t)cellB * CAP;

    float aA0 = 0, aA1 = 0, aA2 = 0, aA3 = 0;
    float aB0 = 0, aB1 = 0, aB2 = 0, aB3 = 0;
    int nmax = nA > nB ? nA : nB;
    for (int i = 0; i < nmax; i += 4) {
        // clamped slot indices: past-the-end lanes re-read slot 0 (L2-hot).
        int jA0 = (i + 0 < nA) ? i + 0 : 0;
        int jA1 = (i + 1 < nA) ? i + 1 : 0;
        int jA2 = (i + 2 < nA) ? i + 2 : 0;
        int jA3 = (i + 3 < nA) ? i + 3 : 0;
        int jB0 = (i + 0 < nB) ? i + 0 : 0;
        int jB1 = (i + 1 < nB) ? i + 1 : 0;
        int jB2 = (i + 2 < nB) ? i + 2 : 0;
        int jB3 = (i + 3 < nB) ? i + 3 : 0;
        // slot values; poison-safe clamp into [0, NPRIME)
        unsigned pA0 = min((unsigned)slA[jA0], NPRIME - 1u);
        unsigned pA1 = min((unsigned)slA[jA1], NPRIME - 1u);
        unsigned pA2 = min((unsigned)slA[jA2], NPRIME - 1u);
        unsigned pA3 = min((unsigned)slA[jA3], NPRIME - 1u);
        unsigned pB0 = min((unsigned)slB[jB0], NPRIME - 1u);
        unsigned pB1 = min((unsigned)slB[jB1], NPRIME - 1u);
        unsigned pB2 = min((unsigned)slB[jB2], NPRIME - 1u);
        unsigned pB3 = min((unsigned)slB[jB3], NPRIME - 1u);
        // 8 independent row gathers in flight
        float vA0 = x[(size_t)pA0 * NCH + lane];
        float vA1 = x[(size_t)pA1 * NCH + lane];
        float vA2 = x[(size_t)pA2 * NCH + lane];
        float vA3 = x[(size_t)pA3 * NCH + lane];
        float vB0 = x[(size_t)pB0 * NCH + lane];
        float vB1 = x[(size_t)pB1 * NCH + lane];
        float vB2 = x[(size_t)pB2 * NCH + lane];
        float vB3 = x[(size_t)pB3 * NCH + lane];
        aA0 += (i + 0 < nA) ? vA0 : 0.0f;
        aA1 += (i + 1 < nA) ? vA1 : 0.0f;
        aA2 += (i + 2 < nA) ? vA2 : 0.0f;
        aA3 += (i + 3 < nA) ? vA3 : 0.0f;
        aB0 += (i + 0 < nB) ? vB0 : 0.0f;
        aB1 += (i + 1 < nB) ? vB1 : 0.0f;
        aB2 += (i + 2 < nB) ? vB2 : 0.0f;
        aB3 += (i + 3 < nB) ? vB3 : 0.0f;
    }
    tile[wave * 2 + 0][lane] = (aA0 + aA1) + (aA2 + aA3);
    tile[wave * 2 + 1][lane] = (aB0 + aB1) + (aB2 + aB3);
    __syncthreads();

    // transposed write: threads 0..511 -> c = t>>3, xyl = (t&7)*4 (float4).
    // 8-lane groups write 128B contiguous row segments (full sectors).
    if (t < 512) {
        int c   = t >> 3;                // 0..63
        int xyl = (t & 7) * 4;           // 0..28
        int xy  = xy0 + xyl;
        if (xy + 3 < CELLS_PER_B) {      // 30000 % 4 == 0
            float4 w;
            w.x = tile[xyl + 0][c];
            w.y = tile[xyl + 1][c];
            w.z = tile[xyl + 2][c];
            w.w = tile[xyl + 3][c];
            *reinterpret_cast<float4*>(out + ((size_t)(b * NCH + c)) * CELLS_PER_B + xy) = w;
        }
    }
}

// ---- fallback (small ws), validated v7 path ----
__global__ __launch_bounds__(256) void lss_bin(
    const float* __restrict__ geom, int* __restrict__ cell)
{
    int p = blockIdx.x * 256 + threadIdx.x;
    if (p >= NPRIME) return;
    cell[p] = compute_cell(geom[3 * p], geom[3 * p + 1], geom[3 * p + 2], p);
}

__global__ __launch_bounds__(256) void lss_scatter_direct(
    const float* __restrict__ x, const int* __restrict__ cell,
    float* __restrict__ out)
{
    int t = blockIdx.x * 256 + threadIdx.x;
    int p = t >> 4;
    if (p >= NPRIME) return;
    int c = cell[p];
    if (c < 0) return;
    int c4 = (t & 15) << 2;
    const float4 xv = *reinterpret_cast<const float4*>(x + (size_t)p * NCH + c4);
    int b  = c / CELLS_PER_B;
    int xy = c - b * CELLS_PER_B;
    float* o = out + ((size_t)(b * NCH + c4)) * CELLS_PER_B + xy;
    atomicAdd(o,                   xv.x);
    atomicAdd(o +     CELLS_PER_B, xv.y);
    atomicAdd(o + 2 * CELLS_PER_B, xv.z);
    atomicAdd(o + 3 * CELLS_PER_B, xv.w);
}

__global__ __launch_bounds__(256) void lss_fused(
    const float* __restrict__ geom, const float* __restrict__ x,
    float* __restrict__ out)
{
    int t = blockIdx.x * 256 + threadIdx.x;
    int p = t >> 4;
    if (p >= NPRIME) return;
    int c = compute_cell(geom[3 * p], geom[3 * p + 1], geom[3 * p + 2], p);
    if (c < 0) return;
    int b  = c / CELLS_PER_B;
    int xy = c - b * CELLS_PER_B;
    int c4 = (t & 15) << 2;
    const float4 xv = *reinterpret_cast<const float4*>(x + (size_t)p * NCH + c4);
    float* o = out + ((size_t)(b * NCH + c4)) * CELLS_PER_B + xy;
    atomicAdd(o,                   xv.x);
    atomicAdd(o +     CELLS_PER_B, xv.y);
    atomicAdd(o + 2 * CELLS_PER_B, xv.z);
    atomicAdd(o + 3 * CELLS_PER_B, xv.w);
}

extern "C" void kernel_launch(void* const* d_in, const int* in_sizes, int n_in,
                              void* d_out, int out_size, void* d_ws, size_t ws_size,
                              hipStream_t stream) {
    const float* geom = (const float*)d_in[0];
    const float* x    = (const float*)d_in[1];
    float* out = (float*)d_out;

    const int bin_blocks = (NPRIME + 255) / 256;

    if (ws_size >= CNT_BYTES + SLOT_BYTES) {
        unsigned* cnt = (unsigned*)d_ws;
        int* slots    = (int*)((char*)d_ws + CNT_BYTES);
        lss_zero<<<(NCELLS + 255) / 256, 256, 0, stream>>>(cnt);
        lss_bin_push<<<bin_blocks, 256, 0, stream>>>(geom, cnt, slots);
        dim3 agrid((CELLS_PER_B + 31) / 32, 4);      // 938 x 4
        lss_accum<<<agrid, 1024, 0, stream>>>(x, cnt, slots, out);
    } else if (ws_size >= CELL_BYTES) {
        int* cell = (int*)d_ws;
        hipMemsetAsync(d_out, 0, (size_t)out_size * sizeof(float), stream);
        lss_bin<<<bin_blocks, 256, 0, stream>>>(geom, cell);
        lss_scatter_direct<<<(NPRIME * 16 + 255) / 256, 256, 0, stream>>>(x, cell, out);
    } else {
        hipMemsetAsync(d_out, 0, (size_t)out_size * sizeof(float), stream);
        lss_fused<<<(NPRIME * 16 + 255) / 256, 256, 0, stream>>>(geom, x, out);
    }
}